// Round 4
// baseline (501.055 us; speedup 1.0000x reference)
//
#include <hip/hip_runtime.h>

typedef _Float16 half8 __attribute__((ext_vector_type(8)));
typedef _Float16 half4 __attribute__((ext_vector_type(4)));
typedef __fp16 fp16x2 __attribute__((ext_vector_type(2)));
typedef short short8 __attribute__((ext_vector_type(8)));
typedef short short4v __attribute__((ext_vector_type(4)));
typedef float floatx4 __attribute__((ext_vector_type(4)));

#define LOG2E 1.4426950408889634f

#define GLDS16(g, l) __builtin_amdgcn_global_load_lds( \
    (const __attribute__((address_space(1))) unsigned int*)(g), \
    (__attribute__((address_space(3))) unsigned int*)(l), 16, 0, 0)

static __device__ __forceinline__ short f2bf(float f){
  union { float f; unsigned u; } v; v.f = f;
  unsigned r = v.u + 0x7fffu + ((v.u >> 16) & 1u);
  return (short)(r >> 16);
}
static __device__ __forceinline__ float bf2f(short s){
  union { unsigned u; float f; } v; v.u = ((unsigned)(unsigned short)s) << 16;
  return v.f;
}

// ---- X/M fp32 -> fragment-major bf16 hi/lo.  Frag layout: [kt(32)][ntile(256)][64][8]
__global__ __launch_bounds__(256) void kconvA(const float* __restrict__ X,
                                              const float* __restrict__ Mm,
                                              short* __restrict__ XFh, short* __restrict__ XFl,
                                              short* __restrict__ MFh, short* __restrict__ MFl){
  int b = blockIdx.x;                       // 512: src=b>>8, ntile=b&255
  int t = threadIdx.x, w = t >> 6, l = t & 63, quad = l >> 4;
  int srcsel = b >> 8, ntile = b & 255;
  const float* A = srcsel ? Mm : X;
  short* oh = srcsel ? MFh : XFh;
  short* ol = srcsel ? MFl : XFl;
  int row = ntile*16 + (l & 15);
  #pragma unroll
  for (int i = 0; i < 8; i++){
    int kt = w*8 + i;
    const float* p = A + (size_t)row*1024 + kt*32 + quad*8;
    float4 v0 = *(const float4*)p, v1 = *(const float4*)(p + 4);
    float vv[8] = {v0.x,v0.y,v0.z,v0.w,v1.x,v1.y,v1.z,v1.w};
    short8 hh, ll;
    #pragma unroll
    for (int j = 0; j < 8; j++){
      short hb = f2bf(vv[j]); hh[j] = hb; ll[j] = f2bf(vv[j] - bf2f(hb));
    }
    size_t off = ((size_t)kt*256 + ntile)*512 + l*8;
    *(short8*)&oh[off] = hh;
    *(short8*)&ol[off] = ll;
  }
}

// ---- Wq/Wk/Wv fp32 [h][1024][64] -> fragment-major bf16 hi/lo, LDS-staged coalesced
__global__ __launch_bounds__(256) void kconvW2(const float* __restrict__ Wq,
                                               const float* __restrict__ Wk,
                                               const float* __restrict__ Wv,
                                               short* __restrict__ WFh, short* __restrict__ WFl){
  __shared__ float T[128][68];
  int bidx = blockIdx.x, g = blockIdx.y;    // bidx 0..47, g 0..7 (4 kt each)
  int mat = bidx >> 4, h = bidx & 15;
  const float* W = (mat == 0 ? Wq : (mat == 1 ? Wk : Wv)) + (size_t)h*65536;
  int t = threadIdx.x, w = t >> 6, l = t & 63, quad = (l >> 4) & 3, fl = l & 15;
  #pragma unroll
  for (int p = 0; p < 32; p++){
    int idx = p*256 + t, row = idx >> 6, col = idx & 63;
    T[row][col] = W[(size_t)(g*128 + row)*64 + col];
  }
  __syncthreads();
  for (int ktl = 0; ktl < 4; ktl++){
    short8 hh, ll;
    #pragma unroll
    for (int j = 0; j < 8; j++){
      float v = T[ktl*32 + quad*8 + j][w*16 + fl];
      short hb = f2bf(v); hh[j] = hb; ll[j] = f2bf(v - bf2f(hb));
    }
    size_t frag = ((size_t)bidx*32 + g*4 + ktl)*4 + w;
    *(short8*)&WFh[frag*512 + l*8] = hh;
    *(short8*)&WFl[frag*512 + l*8] = ll;
  }
}

// ---- mask -> bitmask (row orientation): bits[n*128 + kw] bit i = mask[n][kw*32+i]
__global__ __launch_bounds__(256) void kmaskpack(const int* __restrict__ mask,
                                                 unsigned* __restrict__ bits){
  int w = blockIdx.x * 256 + threadIdx.x;          // 4096*128 words
  const int* p = mask + (size_t)w * 32;
  unsigned b = 0;
  #pragma unroll
  for (int i = 0; i < 32; i++) b |= (p[i] != 0) ? (1u << i) : 0u;
  bits[w] = b;
}

// ---- fp32 [R][C] (z-batch) -> transposed bf16 hi/lo [C][R]  (for Wo)
__global__ __launch_bounds__(256) void ktransw(const float* __restrict__ src,
                                               short* __restrict__ dsth,
                                               short* __restrict__ dstl,
                                               int R, int C){
  __shared__ float tile[32][33];
  size_t boff = (size_t)blockIdx.z * R * C;
  src += boff; dsth += boff; dstl += boff;
  int r0 = blockIdx.y*32, c0 = blockIdx.x*32;
  int t = threadIdx.x, tr = t >> 3, tc = (t & 7)*4;
  const float* s = src + (size_t)(r0 + tr)*C + c0 + tc;
  #pragma unroll
  for (int i = 0; i < 4; i++) tile[tr][tc + i] = s[i];
  __syncthreads();
  short* dh = dsth + (size_t)(c0 + tr)*R + r0 + tc;
  short* dl = dstl + (size_t)(c0 + tr)*R + r0 + tc;
  #pragma unroll
  for (int i = 0; i < 4; i++){
    float v = tile[tc + i][tr];
    short hb = f2bf(v);
    dh[i] = hb; dl[i] = f2bf(v - bf2f(hb));
  }
}

// ---- QKV projection v3: Q blocks (cb<16) as before; cb>=16 computes K AND V for
//      head cb-16 with ONE shared A=M staging (48 MFMA per barrier-pair vs 24).
//      Q/K f16 hi/lo out (Q pre-scaled by log2 e); V as K=16 A-frags f16.
__global__ __launch_bounds__(256,3) void kproj3(
    const short* __restrict__ XFh, const short* __restrict__ XFl,
    const short* __restrict__ MFh, const short* __restrict__ MFl,
    const short* __restrict__ WFh, const short* __restrict__ WFl,
    _Float16* __restrict__ QFh, _Float16* __restrict__ QFl,
    _Float16* __restrict__ KFh, _Float16* __restrict__ KFl,
    _Float16* __restrict__ VF)
{
  __shared__ short AhL[4096], AlL[4096], BhL[4096], BlL[4096];   // 32 KB
  int cb = blockIdx.x, rb = blockIdx.y;
  const bool fused = (cb >= 16);            // cb<16: Q head cb; else K+V head cb-16
  int h = fused ? (cb - 16) : cb;
  const short* Ah = fused ? MFh : XFh;
  const short* Al = fused ? MFl : XFl;
  int t = threadIdx.x, w = t >> 6, l = t & 63, quad = l >> 4, ln = l & 15;
  floatx4 acc[2][8] = {};
  for (int kt = 0; kt < 32; kt++){
    __syncthreads();
    size_t abase = ((size_t)kt*256 + rb*8)*512;
    #pragma unroll
    for (int i = 0; i < 2; i++){
      int cidx = i*256 + t;
      GLDS16(Ah + abase + cidx*8, &AhL[(i*256 + w*64)*8]);
      GLDS16(Al + abase + cidx*8, &AlL[(i*256 + w*64)*8]);
    }
    // B frags: Q -> cbW = cb; K -> cbW = 16+h = cb; V -> cbW = 32+h = cb+16
    size_t bb0 = (((size_t)cb*32 + kt)*4)*512;
    GLDS16(WFh + bb0 + t*8, &BhL[(w*64)*8]);
    GLDS16(WFl + bb0 + t*8, &BlL[(w*64)*8]);
    if (fused){
      size_t bb1 = (((size_t)(cb + 16)*32 + kt)*4)*512;
      GLDS16(WFh + bb1 + t*8, &BhL[(256 + w*64)*8]);
      GLDS16(WFl + bb1 + t*8, &BlL[(256 + w*64)*8]);
    }
    __syncthreads();
    short8 ah[2], al[2];
    #pragma unroll
    for (int mt = 0; mt < 2; mt++){
      ah[mt] = *(short8*)&AhL[(w*2 + mt)*512 + l*8];
      al[mt] = *(short8*)&AlL[(w*2 + mt)*512 + l*8];
    }
    {
      short8 bh[4], bl[4];
      #pragma unroll
      for (int nt = 0; nt < 4; nt++){
        bh[nt] = *(short8*)&BhL[nt*512 + l*8];
        bl[nt] = *(short8*)&BlL[nt*512 + l*8];
      }
      #pragma unroll
      for (int mt = 0; mt < 2; mt++)
        #pragma unroll
        for (int nt = 0; nt < 4; nt++){
          acc[mt][nt] = __builtin_amdgcn_mfma_f32_16x16x32_bf16(ah[mt], bh[nt], acc[mt][nt], 0, 0, 0);
          acc[mt][nt] = __builtin_amdgcn_mfma_f32_16x16x32_bf16(ah[mt], bl[nt], acc[mt][nt], 0, 0, 0);
          acc[mt][nt] = __builtin_amdgcn_mfma_f32_16x16x32_bf16(al[mt], bh[nt], acc[mt][nt], 0, 0, 0);
        }
    }
    if (fused){
      short8 bh[4], bl[4];
      #pragma unroll
      for (int nt = 0; nt < 4; nt++){
        bh[nt] = *(short8*)&BhL[(4 + nt)*512 + l*8];
        bl[nt] = *(short8*)&BlL[(4 + nt)*512 + l*8];
      }
      #pragma unroll
      for (int mt = 0; mt < 2; mt++)
        #pragma unroll
        for (int nt = 0; nt < 4; nt++){
          acc[mt][4+nt] = __builtin_amdgcn_mfma_f32_16x16x32_bf16(ah[mt], bh[nt], acc[mt][4+nt], 0, 0, 0);
          acc[mt][4+nt] = __builtin_amdgcn_mfma_f32_16x16x32_bf16(ah[mt], bl[nt], acc[mt][4+nt], 0, 0, 0);
          acc[mt][4+nt] = __builtin_amdgcn_mfma_f32_16x16x32_bf16(al[mt], bh[nt], acc[mt][4+nt], 0, 0, 0);
        }
    }
  }
  int row0 = rb*128;
  if (!fused){
    // Q write: f16 hi/lo frag layout, pre-scaled by log2 e
    #pragma unroll
    for (int mt = 0; mt < 2; mt++)
      #pragma unroll
      for (int nt = 0; nt < 4; nt++)
        #pragma unroll
        for (int rg = 0; rg < 4; rg++){
          int n = row0 + w*32 + mt*16 + quad*4 + rg;
          int c = nt*16 + ln;
          float v = acc[mt][nt][rg] * LOG2E;
          _Float16 hi = (_Float16)v;
          _Float16 lo = (_Float16)(v - (float)hi);
          int lane2 = (n & 15) + (((c >> 3) & 3) << 4);
          size_t off = (((size_t)h*256 + (n >> 4))*2 + (c >> 5))*512 + lane2*8 + (c & 7);
          QFh[off] = hi; QFl[off] = lo;
        }
  } else {
    // K write from acc[.][0..3]
    #pragma unroll
    for (int mt = 0; mt < 2; mt++)
      #pragma unroll
      for (int nt = 0; nt < 4; nt++)
        #pragma unroll
        for (int rg = 0; rg < 4; rg++){
          int n = row0 + w*32 + mt*16 + quad*4 + rg;
          int c = nt*16 + ln;
          float v = acc[mt][nt][rg];
          _Float16 hi = (_Float16)v;
          _Float16 lo = (_Float16)(v - (float)hi);
          int lane2 = (n & 15) + (((c >> 3) & 3) << 4);
          size_t off = (((size_t)h*256 + (n >> 4))*2 + (c >> 5))*512 + lane2*8 + (c & 7);
          KFh[off] = hi; KFl[off] = lo;
        }
    // V write from acc[.][4..7]: K=16 A-frag layout
    #pragma unroll
    for (int mt = 0; mt < 2; mt++)
      #pragma unroll
      for (int ntv = 0; ntv < 4; ntv++){
        union { fp16x2 h2[2]; unsigned u2[2]; } pu;
        pu.h2[0] = __builtin_amdgcn_cvt_pkrtz(acc[mt][4+ntv][0], acc[mt][4+ntv][1]);
        pu.h2[1] = __builtin_amdgcn_cvt_pkrtz(acc[mt][4+ntv][2], acc[mt][4+ntv][3]);
        size_t base = (((size_t)h*32 + rb)*16 + ntv*4 + w)*512;
        *(uint2*)&VF[base + (quad*16 + ln)*8 + mt*4] = *(uint2*)&pu.u2[0];
      }
  }
}

// ---- flash attention v9: 128-row q blocks (32 q per wave -> HALF the LDS read
//      traffic per q), 64-row kv tiles, K hi/lo AND V all double-buffered ->
//      ONE barrier per iter. 48KB LDS, grid 512 = 2 blocks/CU (2 waves/SIMD).
__global__ __launch_bounds__(256,2) void kattn9(
    const _Float16* __restrict__ QFh, const _Float16* __restrict__ QFl,
    const _Float16* __restrict__ KFh, const _Float16* __restrict__ KFl,
    const _Float16* __restrict__ VF, const unsigned* __restrict__ bits,
    short* __restrict__ Ows)
{
  __shared__ _Float16 KBh[2][4096], KBl[2][4096], VB[2][4096];  // 48 KB
  int bx = blockIdx.x, h = bx & 15, qb = bx >> 4, q0 = qb*128;  // qb 0..31
  int t = threadIdx.x, w = t >> 6, l = t & 63, quad = l >> 4, ln = l & 15;

  // Q as B-fragments; wave w owns 32 q rows (2 subtiles of 16)
  half8 qh[2][2], ql[2][2];
  #pragma unroll
  for (int nt2 = 0; nt2 < 2; nt2++)
    #pragma unroll
    for (int kc = 0; kc < 2; kc++){
      size_t off = (((size_t)h*256 + qb*8 + w*2 + nt2)*2 + kc)*512 + l*8;
      qh[nt2][kc] = *(const half8*)&QFh[off];
      ql[nt2][kc] = *(const half8*)&QFl[off];
    }

  floatx4 o[2][4] = {};                 // O^T: lane q=ln, v = vt*16+quad*4+rg
  float mst[2] = {-1e30f, -1e30f}, lst[2] = {0.f, 0.f};

  const size_t hb = (size_t)h*262144;
  const int cidx0 = t, cidx1 = 256 + t;
  const int ld0 = (w*64)*8, ld1 = (256 + w*64)*8;

  // ---- prologue: stage K[0] (hi+lo) + V[0] into buffer 0
  {
    GLDS16(KFh + hb + cidx0*8, &KBh[0][ld0]);
    GLDS16(KFh + hb + cidx1*8, &KBh[0][ld1]);
    GLDS16(KFl + hb + cidx0*8, &KBl[0][ld0]);
    GLDS16(KFl + hb + cidx1*8, &KBl[0][ld1]);
    #pragma unroll
    for (int i = 0; i < 2; i++){
      int cidx = i*256 + t;
      int lu = cidx >> 6, uoff = (cidx & 63)*8;
      int gu = (lu >> 1)*4 + (lu & 1);                  // vhalf = 0
      GLDS16(VF + hb + (size_t)gu*512 + uoff, &VB[0][(i*256 + w*64)*8]);
    }
  }
  __syncthreads();                                      // drains K0/V0

  int cur = 0;
  for (int kt = 0; kt < 64; kt++){
    int ktn = (kt + 1) & 63, nxt = cur ^ 1;             // wrap -> always valid mem
    // ---- prefetch K[ktn] + V[ktn] into the other buffers (covered by this iter)
    size_t kbn = hb + (size_t)ktn*4096;
    GLDS16(KFh + kbn + cidx0*8, &KBh[nxt][ld0]);
    GLDS16(KFh + kbn + cidx1*8, &KBh[nxt][ld1]);
    GLDS16(KFl + kbn + cidx0*8, &KBl[nxt][ld0]);
    GLDS16(KFl + kbn + cidx1*8, &KBl[nxt][ld1]);
    {
      size_t vbn = hb + (size_t)(ktn >> 1)*8192;
      int vhalf = (ktn & 1)*2;
      #pragma unroll
      for (int i = 0; i < 2; i++){
        int cidx = i*256 + t;
        int lu = cidx >> 6, uoff = (cidx & 63)*8;
        int gu = (lu >> 1)*4 + vhalf + (lu & 1);
        GLDS16(VF + vbn + (size_t)gu*512 + uoff, &VB[nxt][(i*256 + w*64)*8]);
      }
    }
    // mask words for current kt (latency hidden under QK MFMAs)
    uint2 mw[2];
    mw[0] = *(const uint2*)&bits[(size_t)(q0 + w*32 + ln)*128 + kt*2];
    mw[1] = *(const uint2*)&bits[(size_t)(q0 + w*32 + 16 + ln)*128 + kt*2];

    // ---- S^T = Khi*Qhi + Klo*Qhi + Khi*Qlo  (log2-domain; K-frags read once,
    //      each serves BOTH q-subtiles)
    floatx4 st[2][4] = {};
    __builtin_amdgcn_s_setprio(1);
    #pragma unroll
    for (int kc = 0; kc < 2; kc++)
      #pragma unroll
      for (int m8 = 0; m8 < 4; m8++){
        half8 kh = *(half8*)&KBh[cur][(m8*2 + kc)*512 + l*8];
        half8 kl = *(half8*)&KBl[cur][(m8*2 + kc)*512 + l*8];
        #pragma unroll
        for (int nt2 = 0; nt2 < 2; nt2++){
          st[nt2][m8] = __builtin_amdgcn_mfma_f32_16x16x32_f16(kh, qh[nt2][kc], st[nt2][m8], 0, 0, 0);
          st[nt2][m8] = __builtin_amdgcn_mfma_f32_16x16x32_f16(kl, qh[nt2][kc], st[nt2][m8], 0, 0, 0);
          st[nt2][m8] = __builtin_amdgcn_mfma_f32_16x16x32_f16(kh, ql[nt2][kc], st[nt2][m8], 0, 0, 0);
        }
      }
    __builtin_amdgcn_s_setprio(0);

    // ---- mask + online softmax per q-subtile, p = 2^(s - m)
    #pragma unroll
    for (int nt2 = 0; nt2 < 2; nt2++){
      const unsigned* mwp = (const unsigned*)&mw[nt2];
      #pragma unroll
      for (int m8 = 0; m8 < 4; m8++){
        unsigned nib = (mwp[m8 >> 1] >> ((m8 & 1)*16 + quad*4)) & 15u;
        #pragma unroll
        for (int rg = 0; rg < 4; rg++)
          if (!((nib >> rg) & 1u)) st[nt2][m8][rg] = -1e30f;
      }
      float a0 = fmaxf(fmaxf(st[nt2][0][0], st[nt2][0][1]), fmaxf(st[nt2][0][2], st[nt2][0][3]));
      float a1 = fmaxf(fmaxf(st[nt2][1][0], st[nt2][1][1]), fmaxf(st[nt2][1][2], st[nt2][1][3]));
      float a2 = fmaxf(fmaxf(st[nt2][2][0], st[nt2][2][1]), fmaxf(st[nt2][2][2], st[nt2][2][3]));
      float a3 = fmaxf(fmaxf(st[nt2][3][0], st[nt2][3][1]), fmaxf(st[nt2][3][2], st[nt2][3][3]));
      float mx = fmaxf(fmaxf(a0, a1), fmaxf(a2, a3));
      mx = fmaxf(mx, __shfl_xor(mx, 16));
      mx = fmaxf(mx, __shfl_xor(mx, 32));
      // defer-max (T13): skip O-rescale while max growth <= 8 (log2 dom, p<=256)
      if (__any(mx > mst[nt2] + 8.0f)){
        float mnew = fmaxf(mst[nt2], mx);
        float alpha = exp2f(mst[nt2] - mnew);
        mst[nt2] = mnew;
        lst[nt2] *= alpha;
        #pragma unroll
        for (int vt = 0; vt < 4; vt++) o[nt2][vt] *= alpha;
      }
      float ssum = 0.f;
      #pragma unroll
      for (int m8 = 0; m8 < 4; m8++)
        #pragma unroll
        for (int rg = 0; rg < 4; rg++){
          float p = exp2f(st[nt2][m8][rg] - mst[nt2]);
          st[nt2][m8][rg] = p; ssum += p;
        }
      lst[nt2] += ssum;       // per-lane partial; quad-uniform alpha keeps it exact
    }

    // ---- PV: P C-layout == B-operand of 16x16x16f16 (k = quad*4+rg);
    //      V-frags read once, each serves BOTH q-subtiles
    __builtin_amdgcn_s_setprio(1);
    #pragma unroll
    for (int p = 0; p < 2; p++){
      half8 vfp[4];
      #pragma unroll
      for (int vt = 0; vt < 4; vt++)
        vfp[vt] = *(half8*)&VB[cur][((vt*2 + p)*512) + l*8];
      #pragma unroll
      for (int sub = 0; sub < 2; sub++){
        int m8 = p*2 + sub;
        #pragma unroll
        for (int nt2 = 0; nt2 < 2; nt2++){
          union { fp16x2 h2[2]; half4 h4; } pu;
          pu.h2[0] = __builtin_amdgcn_cvt_pkrtz(st[nt2][m8][0], st[nt2][m8][1]);
          pu.h2[1] = __builtin_amdgcn_cvt_pkrtz(st[nt2][m8][2], st[nt2][m8][3]);
          #pragma unroll
          for (int vt = 0; vt < 4; vt++){
            half4 va = sub ? __builtin_shufflevector(vfp[vt], vfp[vt], 4,5,6,7)
                           : __builtin_shufflevector(vfp[vt], vfp[vt], 0,1,2,3);
            o[nt2][vt] = __builtin_amdgcn_mfma_f32_16x16x16f16(va, pu.h4, o[nt2][vt], 0, 0, 0);
          }
        }
      }
    }
    __builtin_amdgcn_s_setprio(0);

    __syncthreads();    // single barrier: drains this iter's prefetch (vmcnt 0)
                        // and fences buffer reuse across waves
    cur = nxt;
  }

  // epilogue: reduce lst across lane-halves, normalize, O^T -> Ows
  #pragma unroll
  for (int nt2 = 0; nt2 < 2; nt2++){
    float li = lst[nt2];
    li += __shfl_xor(li, 16);
    li += __shfl_xor(li, 32);
    float inv = (li > 0.f) ? (1.f / li) : 0.f;
    int n = q0 + w*32 + nt2*16 + ln;
    #pragma unroll
    for (int vt = 0; vt < 4; vt++){
      short4v pk;
      #pragma unroll
      for (int rg = 0; rg < 4; rg++) pk[rg] = f2bf(o[nt2][vt][rg]*inv);
      *(short4v*)&Ows[(size_t)n*1024 + h*64 + vt*16 + quad*4] = pk;
    }
  }
}

// ---- Y[f32] = O[4096x1024 bf16] @ Wot[1024x1024 bf16 B^T rows]
__global__ __launch_bounds__(256,2) void kfinal(const short* __restrict__ Ain,
                                                const short* __restrict__ Bt,
                                                float* __restrict__ Y)
{
  __shared__ short Al[128*48];
  __shared__ short Bl[64*48];
  int cb = blockIdx.x, rb = blockIdx.y;
  int row0 = rb*128, col0 = cb*64;
  int t = threadIdx.x, w = t >> 6, l = t & 63, quad = l >> 4, ln = l & 15;
  floatx4 acc[2][4] = {};
  for (int d0 = 0; d0 < 1024; d0 += 32){
    #pragma unroll
    for (int i = 0; i < 2; i++){
      int u = t + i*256, r = u >> 2, s = u & 3;
      *(int4*)&Al[r*48 + s*8] = *(const int4*)&Ain[(size_t)(row0 + r)*1024 + d0 + s*8];
    }
    { int r = t >> 2, s = t & 3;
      *(int4*)&Bl[r*48 + s*8] = *(const int4*)&Bt[(size_t)(col0 + r)*1024 + d0 + s*8]; }
    __syncthreads();
    short8 bf[4];
    #pragma unroll
    for (int nt = 0; nt < 4; nt++) bf[nt] = *(short8*)&Bl[(nt*16 + ln)*48 + quad*8];
    #pragma unroll
    for (int mt = 0; mt < 2; mt++){
      short8 af = *(short8*)&Al[(w*32 + mt*16 + ln)*48 + quad*8];
      #pragma unroll
      for (int nt = 0; nt < 4; nt++)
        acc[mt][nt] = __builtin_amdgcn_mfma_f32_16x16x32_bf16(af, bf[nt], acc[mt][nt], 0, 0, 0);
    }
    __syncthreads();
  }
  #pragma unroll
  for (int mt = 0; mt < 2; mt++)
    #pragma unroll
    for (int nt = 0; nt < 4; nt++)
      #pragma unroll
      for (int rg = 0; rg < 4; rg++){
        int n = row0 + w*32 + mt*16 + quad*4 + rg;
        int c = col0 + nt*16 + ln;
        Y[(size_t)n*1024 + c] = acc[mt][nt][rg];
      }
}

extern "C" void kernel_launch(void* const* d_in, const int* in_sizes, int n_in,
                              void* d_out, int out_size, void* d_ws, size_t ws_size,
                              hipStream_t stream){
  (void)in_sizes; (void)n_in; (void)out_size; (void)ws_size;
  const float* X    = (const float*)d_in[0];
  const float* Mm   = (const float*)d_in[1];
  const int*   mask = (const int*)d_in[2];
  const float* Wq   = (const float*)d_in[3];
  const float* Wk   = (const float*)d_in[4];
  const float* Wv   = (const float*)d_in[5];
  const float* Wo   = (const float*)d_in[6];
  float* Y = (float*)d_out;
  char* ws = (char*)d_ws;
  const size_t MB = 1024*1024;
  short*    XFh   = (short*)   (ws +  0*MB);   // dead after kproj3
  short*    XFl   = (short*)   (ws +  8*MB);   // dead after kproj3
  short*    MFh   = (short*)   (ws + 16*MB);
  short*    MFl   = (short*)   (ws + 24*MB);
  short*    WFh   = (short*)   (ws + 32*MB);   // 6MB
  short*    WFl   = (short*)   (ws + 38*MB);   // 6MB
  unsigned* bits  = (unsigned*)(ws + 44*MB);   // 2MB  [4096 n][128 kw]
  _Float16* QFh   = (_Float16*)(ws + 46*MB);
  _Float16* QFl   = (_Float16*)(ws + 54*MB);
  _Float16* KFh   = (_Float16*)(ws + 62*MB);
  _Float16* KFl   = (_Float16*)(ws + 70*MB);
  _Float16* VF    = (_Float16*)(ws + 78*MB);   // 8MB, K=16 A-frag layout
  short*    Ows   = (short*)   (ws +  0*MB);   // alias XFh (post-kproj3)
  short*    Wot   = (short*)   (ws +  8*MB);   // alias XFl
  short*    Wotl  = (short*)   (ws + 10*MB);

  kconvA<<<512, 256, 0, stream>>>(X, Mm, XFh, XFl, MFh, MFl);
  kconvW2<<<dim3(48,8), 256, 0, stream>>>(Wq, Wk, Wv, WFh, WFl);
  kmaskpack<<<2048, 256, 0, stream>>>(mask, bits);
  kproj3<<<dim3(32,32), 256, 0, stream>>>(XFh, XFl, MFh, MFl, WFh, WFl,
                                          QFh, QFl, KFh, KFl, VF);
  ktransw<<<dim3(32,32,1), 256, 0, stream>>>(Wo, Wot, Wotl, 1024, 1024);
  kattn9<<<512, 256, 0, stream>>>(QFh, QFl, KFh, KFl, VF, bits, Ows);
  kfinal<<<dim3(16,32), 256, 0, stream>>>(Ows, Wot, Y);
}

// Round 5
// 485.355 us; speedup vs baseline: 1.0323x; 1.0323x over previous
//
#include <hip/hip_runtime.h>

typedef _Float16 half8 __attribute__((ext_vector_type(8)));
typedef _Float16 half4 __attribute__((ext_vector_type(4)));
typedef __fp16 fp16x2 __attribute__((ext_vector_type(2)));
typedef short short8 __attribute__((ext_vector_type(8)));
typedef short short4v __attribute__((ext_vector_type(4)));
typedef float floatx4 __attribute__((ext_vector_type(4)));

#define LOG2E 1.4426950408889634f

#define GLDS16(g, l) __builtin_amdgcn_global_load_lds( \
    (const __attribute__((address_space(1))) unsigned int*)(g), \
    (__attribute__((address_space(3))) unsigned int*)(l), 16, 0, 0)

static __device__ __forceinline__ short f2bf(float f){
  union { float f; unsigned u; } v; v.f = f;
  unsigned r = v.u + 0x7fffu + ((v.u >> 16) & 1u);
  return (short)(r >> 16);
}
static __device__ __forceinline__ float bf2f(short s){
  union { unsigned u; float f; } v; v.u = ((unsigned)(unsigned short)s) << 16;
  return v.f;
}

// ---- X/M fp32 -> fragment-major bf16 hi/lo.  Frag layout: [kt(32)][ntile(256)][64][8]
__global__ __launch_bounds__(256) void kconvA(const float* __restrict__ X,
                                              const float* __restrict__ Mm,
                                              short* __restrict__ XFh, short* __restrict__ XFl,
                                              short* __restrict__ MFh, short* __restrict__ MFl){
  int b = blockIdx.x;                       // 512: src=b>>8, ntile=b&255
  int t = threadIdx.x, w = t >> 6, l = t & 63, quad = l >> 4;
  int srcsel = b >> 8, ntile = b & 255;
  const float* A = srcsel ? Mm : X;
  short* oh = srcsel ? MFh : XFh;
  short* ol = srcsel ? MFl : XFl;
  int row = ntile*16 + (l & 15);
  #pragma unroll
  for (int i = 0; i < 8; i++){
    int kt = w*8 + i;
    const float* p = A + (size_t)row*1024 + kt*32 + quad*8;
    float4 v0 = *(const float4*)p, v1 = *(const float4*)(p + 4);
    float vv[8] = {v0.x,v0.y,v0.z,v0.w,v1.x,v1.y,v1.z,v1.w};
    short8 hh, ll;
    #pragma unroll
    for (int j = 0; j < 8; j++){
      short hb = f2bf(vv[j]); hh[j] = hb; ll[j] = f2bf(vv[j] - bf2f(hb));
    }
    size_t off = ((size_t)kt*256 + ntile)*512 + l*8;
    *(short8*)&oh[off] = hh;
    *(short8*)&ol[off] = ll;
  }
}

// ---- Wq/Wk/Wv fp32 [h][1024][64] -> fragment-major bf16 hi/lo, LDS-staged coalesced
__global__ __launch_bounds__(256) void kconvW2(const float* __restrict__ Wq,
                                               const float* __restrict__ Wk,
                                               const float* __restrict__ Wv,
                                               short* __restrict__ WFh, short* __restrict__ WFl){
  __shared__ float T[128][68];
  int bidx = blockIdx.x, g = blockIdx.y;    // bidx 0..47, g 0..7 (4 kt each)
  int mat = bidx >> 4, h = bidx & 15;
  const float* W = (mat == 0 ? Wq : (mat == 1 ? Wk : Wv)) + (size_t)h*65536;
  int t = threadIdx.x, w = t >> 6, l = t & 63, quad = (l >> 4) & 3, fl = l & 15;
  #pragma unroll
  for (int p = 0; p < 32; p++){
    int idx = p*256 + t, row = idx >> 6, col = idx & 63;
    T[row][col] = W[(size_t)(g*128 + row)*64 + col];
  }
  __syncthreads();
  for (int ktl = 0; ktl < 4; ktl++){
    short8 hh, ll;
    #pragma unroll
    for (int j = 0; j < 8; j++){
      float v = T[ktl*32 + quad*8 + j][w*16 + fl];
      short hb = f2bf(v); hh[j] = hb; ll[j] = f2bf(v - bf2f(hb));
    }
    size_t frag = ((size_t)bidx*32 + g*4 + ktl)*4 + w;
    *(short8*)&WFh[frag*512 + l*8] = hh;
    *(short8*)&WFl[frag*512 + l*8] = ll;
  }
}

// ---- mask -> bitmask (row orientation): bits[n*128 + kw] bit i = mask[n][kw*32+i]
__global__ __launch_bounds__(256) void kmaskpack(const int* __restrict__ mask,
                                                 unsigned* __restrict__ bits){
  int w = blockIdx.x * 256 + threadIdx.x;          // 4096*128 words
  const int* p = mask + (size_t)w * 32;
  unsigned b = 0;
  #pragma unroll
  for (int i = 0; i < 32; i++) b |= (p[i] != 0) ? (1u << i) : 0u;
  bits[w] = b;
}

// ---- fp32 [R][C] (z-batch) -> transposed bf16 hi/lo [C][R]  (for Wo)
__global__ __launch_bounds__(256) void ktransw(const float* __restrict__ src,
                                               short* __restrict__ dsth,
                                               short* __restrict__ dstl,
                                               int R, int C){
  __shared__ float tile[32][33];
  size_t boff = (size_t)blockIdx.z * R * C;
  src += boff; dsth += boff; dstl += boff;
  int r0 = blockIdx.y*32, c0 = blockIdx.x*32;
  int t = threadIdx.x, tr = t >> 3, tc = (t & 7)*4;
  const float* s = src + (size_t)(r0 + tr)*C + c0 + tc;
  #pragma unroll
  for (int i = 0; i < 4; i++) tile[tr][tc + i] = s[i];
  __syncthreads();
  short* dh = dsth + (size_t)(c0 + tr)*R + r0 + tc;
  short* dl = dstl + (size_t)(c0 + tr)*R + r0 + tc;
  #pragma unroll
  for (int i = 0; i < 4; i++){
    float v = tile[tc + i][tr];
    short hb = f2bf(v);
    dh[i] = hb; dl[i] = f2bf(v - bf2f(hb));
  }
}

// ---- QKV projection v4: ALL blocks run the wide 128-col path (48 MFMA/iter).
//      cb<8: Q for heads 2cb,2cb+1 (one shared A=X staging).
//      cb>=8: K AND V for head cb-8 (one shared A=M staging).
//      Grid 24x32 = 768 blocks = exactly 3/CU, one tranche.
__global__ __launch_bounds__(256,3) void kproj4(
    const short* __restrict__ XFh, const short* __restrict__ XFl,
    const short* __restrict__ MFh, const short* __restrict__ MFl,
    const short* __restrict__ WFh, const short* __restrict__ WFl,
    _Float16* __restrict__ QFh, _Float16* __restrict__ QFl,
    _Float16* __restrict__ KFh, _Float16* __restrict__ KFl,
    _Float16* __restrict__ VF)
{
  __shared__ short AhL[4096], AlL[4096], BhL[4096], BlL[4096];   // 32 KB
  int cb = blockIdx.x, rb = blockIdx.y;
  const bool isQ = (cb < 8);
  // B-frag sources: Q -> (2cb, 2cb+1); KV head h=cb-8 -> K=16+h=8+cb, V=32+h=24+cb
  int src0 = isQ ? (2*cb)     : (8 + cb);
  int src1 = isQ ? (2*cb + 1) : (24 + cb);
  const short* Ah = isQ ? XFh : MFh;
  const short* Al = isQ ? XFl : MFl;
  int t = threadIdx.x, w = t >> 6, l = t & 63, quad = l >> 4, ln = l & 15;
  floatx4 acc[2][8] = {};
  for (int kt = 0; kt < 32; kt++){
    __syncthreads();
    size_t abase = ((size_t)kt*256 + rb*8)*512;
    #pragma unroll
    for (int i = 0; i < 2; i++){
      int cidx = i*256 + t;
      GLDS16(Ah + abase + cidx*8, &AhL[(i*256 + w*64)*8]);
      GLDS16(Al + abase + cidx*8, &AlL[(i*256 + w*64)*8]);
    }
    size_t bb0 = (((size_t)src0*32 + kt)*4)*512;
    size_t bb1 = (((size_t)src1*32 + kt)*4)*512;
    GLDS16(WFh + bb0 + t*8, &BhL[(w*64)*8]);
    GLDS16(WFl + bb0 + t*8, &BlL[(w*64)*8]);
    GLDS16(WFh + bb1 + t*8, &BhL[(256 + w*64)*8]);
    GLDS16(WFl + bb1 + t*8, &BlL[(256 + w*64)*8]);
    __syncthreads();
    short8 ah[2], al[2];
    #pragma unroll
    for (int mt = 0; mt < 2; mt++){
      ah[mt] = *(short8*)&AhL[(w*2 + mt)*512 + l*8];
      al[mt] = *(short8*)&AlL[(w*2 + mt)*512 + l*8];
    }
    #pragma unroll
    for (int half = 0; half < 2; half++){
      short8 bh[4], bl[4];
      #pragma unroll
      for (int nt = 0; nt < 4; nt++){
        bh[nt] = *(short8*)&BhL[(half*4 + nt)*512 + l*8];
        bl[nt] = *(short8*)&BlL[(half*4 + nt)*512 + l*8];
      }
      #pragma unroll
      for (int mt = 0; mt < 2; mt++)
        #pragma unroll
        for (int nt = 0; nt < 4; nt++){
          int a = half*4 + nt;
          acc[mt][a] = __builtin_amdgcn_mfma_f32_16x16x32_bf16(ah[mt], bh[nt], acc[mt][a], 0, 0, 0);
          acc[mt][a] = __builtin_amdgcn_mfma_f32_16x16x32_bf16(ah[mt], bl[nt], acc[mt][a], 0, 0, 0);
          acc[mt][a] = __builtin_amdgcn_mfma_f32_16x16x32_bf16(al[mt], bh[nt], acc[mt][a], 0, 0, 0);
        }
    }
  }
  int row0 = rb*128;
  if (isQ){
    // Q write: heads 2cb + (a>>2); f16 hi/lo frag layout, pre-scaled by log2 e
    #pragma unroll
    for (int mt = 0; mt < 2; mt++)
      #pragma unroll
      for (int a = 0; a < 8; a++)
        #pragma unroll
        for (int rg = 0; rg < 4; rg++){
          int h = 2*cb + (a >> 2);
          int n = row0 + w*32 + mt*16 + quad*4 + rg;
          int c = (a & 3)*16 + ln;
          float v = acc[mt][a][rg] * LOG2E;
          _Float16 hi = (_Float16)v;
          _Float16 lo = (_Float16)(v - (float)hi);
          int lane2 = (n & 15) + (((c >> 3) & 3) << 4);
          size_t off = (((size_t)h*256 + (n >> 4))*2 + (c >> 5))*512 + lane2*8 + (c & 7);
          QFh[off] = hi; QFl[off] = lo;
        }
  } else {
    int h = cb - 8;
    // K write from acc[.][0..3]
    #pragma unroll
    for (int mt = 0; mt < 2; mt++)
      #pragma unroll
      for (int nt = 0; nt < 4; nt++)
        #pragma unroll
        for (int rg = 0; rg < 4; rg++){
          int n = row0 + w*32 + mt*16 + quad*4 + rg;
          int c = nt*16 + ln;
          float v = acc[mt][nt][rg];
          _Float16 hi = (_Float16)v;
          _Float16 lo = (_Float16)(v - (float)hi);
          int lane2 = (n & 15) + (((c >> 3) & 3) << 4);
          size_t off = (((size_t)h*256 + (n >> 4))*2 + (c >> 5))*512 + lane2*8 + (c & 7);
          KFh[off] = hi; KFl[off] = lo;
        }
    // V write from acc[.][4..7]: K=16 A-frag layout
    #pragma unroll
    for (int mt = 0; mt < 2; mt++)
      #pragma unroll
      for (int ntv = 0; ntv < 4; ntv++){
        union { fp16x2 h2[2]; unsigned u2[2]; } pu;
        pu.h2[0] = __builtin_amdgcn_cvt_pkrtz(acc[mt][4+ntv][0], acc[mt][4+ntv][1]);
        pu.h2[1] = __builtin_amdgcn_cvt_pkrtz(acc[mt][4+ntv][2], acc[mt][4+ntv][3]);
        size_t base = (((size_t)h*32 + rb)*16 + ntv*4 + w)*512;
        *(uint2*)&VF[base + (quad*16 + ln)*8 + mt*4] = *(uint2*)&pu.u2[0];
      }
  }
}

// ---- flash attention v8 (R3 version, 219us): 64-row q blocks, K dbuf prefetch,
//      V staged post-PV, setprio on MFMA clusters, per-lane lst partials.
__global__ __launch_bounds__(256,4) void kattn8(
    const _Float16* __restrict__ QFh, const _Float16* __restrict__ QFl,
    const _Float16* __restrict__ KFh, const _Float16* __restrict__ KFl,
    const _Float16* __restrict__ VF, const unsigned* __restrict__ bits,
    short* __restrict__ Ows)
{
  __shared__ _Float16 KBh[2][4096], KBl[2][4096], VB[4096];     // 40 KB
  int bx = blockIdx.x, h = bx & 15, qb = bx >> 4, q0 = qb*64;   // qb 0..63
  int t = threadIdx.x, w = t >> 6, l = t & 63, quad = l >> 4, ln = l & 15;

  // Q as B-fragments (col q = ln, k = quad*8+j per 32-d chunk); wave w owns 16 q rows
  half8 qh[2], ql[2];
  #pragma unroll
  for (int kc = 0; kc < 2; kc++){
    size_t off = (((size_t)h*256 + qb*4 + w)*2 + kc)*512 + l*8;
    qh[kc] = *(const half8*)&QFh[off];
    ql[kc] = *(const half8*)&QFl[off];
  }

  floatx4 o[4] = {};                          // O^T: lane q=ln, v = vt*16+quad*4+rg
  float mst = -1e30f, lst = 0.f;              // lst: per-lane partial (reduced at end)

  const size_t hb = (size_t)h*262144;
  const int cidx0 = t, cidx1 = 256 + t;
  const int ld0 = (w*64)*8, ld1 = (256 + w*64)*8;

  // ---- prologue: stage K[0] (hi+lo) + V[0], prefetch mask[0]
  {
    GLDS16(KFh + hb + cidx0*8, &KBh[0][ld0]);
    GLDS16(KFh + hb + cidx1*8, &KBh[0][ld1]);
    GLDS16(KFl + hb + cidx0*8, &KBl[0][ld0]);
    GLDS16(KFl + hb + cidx1*8, &KBl[0][ld1]);
    #pragma unroll
    for (int i = 0; i < 2; i++){
      int cidx = i*256 + t;
      int lu = cidx >> 6, uoff = (cidx & 63)*8;
      int gu = (lu >> 1)*4 + (lu & 1);                  // vhalf = 0
      GLDS16(VF + hb + (size_t)gu*512 + uoff, &VB[(i*256 + w*64)*8]);
    }
  }
  uint2 mwv = *(const uint2*)&bits[(size_t)(q0 + w*16 + ln)*128];
  __syncthreads();                                      // drains K0/V0

  int cur = 0;
  for (int kt = 0; kt < 64; kt++){
    int ktn = (kt + 1) & 63;                            // wraps -> always valid mem
    // ---- prefetch K[ktn] into the other buffer (covered by QK+softmax below)
    size_t kbn = hb + (size_t)ktn*4096;
    GLDS16(KFh + kbn + cidx0*8, &KBh[cur^1][ld0]);
    GLDS16(KFh + kbn + cidx1*8, &KBh[cur^1][ld1]);
    GLDS16(KFl + kbn + cidx0*8, &KBl[cur^1][ld0]);
    GLDS16(KFl + kbn + cidx1*8, &KBl[cur^1][ld1]);
    uint2 mwn = *(const uint2*)&bits[(size_t)(q0 + w*16 + ln)*128 + ktn*2];

    // ---- S^T = Khi*Qhi + Klo*Qhi + Khi*Qlo  (log2-domain; from KB[cur])
    floatx4 st[4] = {};
    __builtin_amdgcn_s_setprio(1);
    #pragma unroll
    for (int kc = 0; kc < 2; kc++)
      #pragma unroll
      for (int m8 = 0; m8 < 4; m8++){
        half8 kh = *(half8*)&KBh[cur][(m8*2 + kc)*512 + l*8];
        half8 kl = *(half8*)&KBl[cur][(m8*2 + kc)*512 + l*8];
        st[m8] = __builtin_amdgcn_mfma_f32_16x16x32_f16(kh, qh[kc], st[m8], 0, 0, 0);
        st[m8] = __builtin_amdgcn_mfma_f32_16x16x32_f16(kl, qh[kc], st[m8], 0, 0, 0);
        st[m8] = __builtin_amdgcn_mfma_f32_16x16x32_f16(kh, ql[kc], st[m8], 0, 0, 0);
      }
    __builtin_amdgcn_s_setprio(0);

    // ---- mask + online softmax (register bit-test), p = 2^(s - m)
    {
      const unsigned mwp[2] = {mwv.x, mwv.y};
      #pragma unroll
      for (int m8 = 0; m8 < 4; m8++){
        unsigned nib = (mwp[m8 >> 1] >> ((m8 & 1)*16 + quad*4)) & 15u;
        #pragma unroll
        for (int rg = 0; rg < 4; rg++)
          if (!((nib >> rg) & 1u)) st[m8][rg] = -1e30f;
      }
      // max tree (max3-fusable)
      float a0 = fmaxf(fmaxf(st[0][0], st[0][1]), fmaxf(st[0][2], st[0][3]));
      float a1 = fmaxf(fmaxf(st[1][0], st[1][1]), fmaxf(st[1][2], st[1][3]));
      float a2 = fmaxf(fmaxf(st[2][0], st[2][1]), fmaxf(st[2][2], st[2][3]));
      float a3 = fmaxf(fmaxf(st[3][0], st[3][1]), fmaxf(st[3][2], st[3][3]));
      float mx = fmaxf(fmaxf(a0, a1), fmaxf(a2, a3));
      mx = fmaxf(mx, __shfl_xor(mx, 16));
      mx = fmaxf(mx, __shfl_xor(mx, 32));
      // defer-max (T13): skip O-rescale while max growth <= 8 (log2 dom, p<=256)
      if (__any(mx > mst + 8.0f)){
        float mnew = fmaxf(mst, mx);
        float alpha = exp2f(mst - mnew);
        mst = mnew;
        lst *= alpha;
        #pragma unroll
        for (int vt = 0; vt < 4; vt++) o[vt] *= alpha;
      }
      float ssum = 0.f;
      #pragma unroll
      for (int m8 = 0; m8 < 4; m8++)
        #pragma unroll
        for (int rg = 0; rg < 4; rg++){
          float p = exp2f(st[m8][rg] - mst);
          st[m8][rg] = p; ssum += p;
        }
      lst += ssum;            // per-lane partial; quad-uniform alpha keeps it exact
    }
    mwv = mwn;

    __syncthreads();    // #1: V[kt] (staged end of prev iter) + K[ktn] drained

    // ---- PV: P C-layout == B-operand of 16x16x16f16 (k = quad*4+rg)
    __builtin_amdgcn_s_setprio(1);
    #pragma unroll
    for (int p = 0; p < 2; p++){
      half8 vfp[4];
      #pragma unroll
      for (int vt = 0; vt < 4; vt++)
        vfp[vt] = *(half8*)&VB[((vt*2 + p)*512) + l*8];
      #pragma unroll
      for (int sub = 0; sub < 2; sub++){
        int m8 = p*2 + sub;
        union { fp16x2 h2[2]; half4 h4; } pu;
        pu.h2[0] = __builtin_amdgcn_cvt_pkrtz(st[m8][0], st[m8][1]);
        pu.h2[1] = __builtin_amdgcn_cvt_pkrtz(st[m8][2], st[m8][3]);
        #pragma unroll
        for (int vt = 0; vt < 4; vt++){
          half4 va = sub ? __builtin_shufflevector(vfp[vt], vfp[vt], 4,5,6,7)
                         : __builtin_shufflevector(vfp[vt], vfp[vt], 0,1,2,3);
          o[vt] = __builtin_amdgcn_mfma_f32_16x16x16f16(va, pu.h4, o[vt], 0, 0, 0);
        }
      }
    }
    __builtin_amdgcn_s_setprio(0);

    __syncthreads();    // #2: all waves done reading VB

    // ---- stage V[ktn] (covered by next iter's QK+softmax)
    {
      size_t vbn = hb + (size_t)(ktn >> 1)*8192;
      int vhalf = (ktn & 1)*2;
      #pragma unroll
      for (int i = 0; i < 2; i++){
        int cidx = i*256 + t;
        int lu = cidx >> 6, uoff = (cidx & 63)*8;
        int gu = (lu >> 1)*4 + vhalf + (lu & 1);
        GLDS16(VF + vbn + (size_t)gu*512 + uoff, &VB[(i*256 + w*64)*8]);
      }
    }
    cur ^= 1;
  }

  // epilogue: reduce lst across the quad-group, normalize, O^T -> Ows
  {
    lst += __shfl_xor(lst, 16);
    lst += __shfl_xor(lst, 32);
    float inv = (lst > 0.f) ? (1.f / lst) : 0.f;
    int n = q0 + w*16 + ln;
    #pragma unroll
    for (int vt = 0; vt < 4; vt++){
      short4v pk;
      #pragma unroll
      for (int rg = 0; rg < 4; rg++) pk[rg] = f2bf(o[vt][rg]*inv);
      *(short4v*)&Ows[(size_t)n*1024 + h*64 + vt*16 + quad*4] = pk;
    }
  }
}

// ---- Y[f32] = O[4096x1024 bf16] @ Wot[1024x1024 bf16 B^T rows]
__global__ __launch_bounds__(256,2) void kfinal(const short* __restrict__ Ain,
                                                const short* __restrict__ Bt,
                                                float* __restrict__ Y)
{
  __shared__ short Al[128*48];
  __shared__ short Bl[64*48];
  int cb = blockIdx.x, rb = blockIdx.y;
  int row0 = rb*128, col0 = cb*64;
  int t = threadIdx.x, w = t >> 6, l = t & 63, quad = l >> 4, ln = l & 15;
  floatx4 acc[2][4] = {};
  for (int d0 = 0; d0 < 1024; d0 += 32){
    #pragma unroll
    for (int i = 0; i < 2; i++){
      int u = t + i*256, r = u >> 2, s = u & 3;
      *(int4*)&Al[r*48 + s*8] = *(const int4*)&Ain[(size_t)(row0 + r)*1024 + d0 + s*8];
    }
    { int r = t >> 2, s = t & 3;
      *(int4*)&Bl[r*48 + s*8] = *(const int4*)&Bt[(size_t)(col0 + r)*1024 + d0 + s*8]; }
    __syncthreads();
    short8 bf[4];
    #pragma unroll
    for (int nt = 0; nt < 4; nt++) bf[nt] = *(short8*)&Bl[(nt*16 + ln)*48 + quad*8];
    #pragma unroll
    for (int mt = 0; mt < 2; mt++){
      short8 af = *(short8*)&Al[(w*32 + mt*16 + ln)*48 + quad*8];
      #pragma unroll
      for (int nt = 0; nt < 4; nt++)
        acc[mt][nt] = __builtin_amdgcn_mfma_f32_16x16x32_bf16(af, bf[nt], acc[mt][nt], 0, 0, 0);
    }
    __syncthreads();
  }
  #pragma unroll
  for (int mt = 0; mt < 2; mt++)
    #pragma unroll
    for (int nt = 0; nt < 4; nt++)
      #pragma unroll
      for (int rg = 0; rg < 4; rg++){
        int n = row0 + w*32 + mt*16 + quad*4 + rg;
        int c = col0 + nt*16 + ln;
        Y[(size_t)n*1024 + c] = acc[mt][nt][rg];
      }
}

extern "C" void kernel_launch(void* const* d_in, const int* in_sizes, int n_in,
                              void* d_out, int out_size, void* d_ws, size_t ws_size,
                              hipStream_t stream){
  (void)in_sizes; (void)n_in; (void)out_size; (void)ws_size;
  const float* X    = (const float*)d_in[0];
  const float* Mm   = (const float*)d_in[1];
  const int*   mask = (const int*)d_in[2];
  const float* Wq   = (const float*)d_in[3];
  const float* Wk   = (const float*)d_in[4];
  const float* Wv   = (const float*)d_in[5];
  const float* Wo   = (const float*)d_in[6];
  float* Y = (float*)d_out;
  char* ws = (char*)d_ws;
  const size_t MB = 1024*1024;
  short*    XFh   = (short*)   (ws +  0*MB);   // dead after kproj4
  short*    XFl   = (short*)   (ws +  8*MB);   // dead after kproj4
  short*    MFh   = (short*)   (ws + 16*MB);
  short*    MFl   = (short*)   (ws + 24*MB);
  short*    WFh   = (short*)   (ws + 32*MB);   // 6MB
  short*    WFl   = (short*)   (ws + 38*MB);   // 6MB
  unsigned* bits  = (unsigned*)(ws + 44*MB);   // 2MB  [4096 n][128 kw]
  _Float16* QFh   = (_Float16*)(ws + 46*MB);
  _Float16* QFl   = (_Float16*)(ws + 54*MB);
  _Float16* KFh   = (_Float16*)(ws + 62*MB);
  _Float16* KFl   = (_Float16*)(ws + 70*MB);
  _Float16* VF    = (_Float16*)(ws + 78*MB);   // 8MB, K=16 A-frag layout
  short*    Ows   = (short*)   (ws +  0*MB);   // alias XFh (post-kproj4)
  short*    Wot   = (short*)   (ws +  8*MB);   // alias XFl
  short*    Wotl  = (short*)   (ws + 10*MB);

  kconvA<<<512, 256, 0, stream>>>(X, Mm, XFh, XFl, MFh, MFl);
  kconvW2<<<dim3(48,8), 256, 0, stream>>>(Wq, Wk, Wv, WFh, WFl);
  kmaskpack<<<2048, 256, 0, stream>>>(mask, bits);
  kproj4<<<dim3(24,32), 256, 0, stream>>>(XFh, XFl, MFh, MFl, WFh, WFl,
                                          QFh, QFl, KFh, KFl, VF);
  ktransw<<<dim3(32,32,1), 256, 0, stream>>>(Wo, Wot, Wotl, 1024, 1024);
  kattn8<<<1024, 256, 0, stream>>>(QFh, QFl, KFh, KFl, VF, bits, Ows);
  kfinal<<<dim3(16,32), 256, 0, stream>>>(Ows, Wot, Y);
}

// Round 6
// 445.002 us; speedup vs baseline: 1.1260x; 1.0907x over previous
//
#include <hip/hip_runtime.h>

typedef _Float16 half8 __attribute__((ext_vector_type(8)));
typedef _Float16 half4 __attribute__((ext_vector_type(4)));
typedef __fp16 fp16x2 __attribute__((ext_vector_type(2)));
typedef short short8 __attribute__((ext_vector_type(8)));
typedef short short4v __attribute__((ext_vector_type(4)));
typedef float floatx4 __attribute__((ext_vector_type(4)));

#define LOG2E 1.4426950408889634f

#define GLDS16(g, l) __builtin_amdgcn_global_load_lds( \
    (const __attribute__((address_space(1))) unsigned int*)(g), \
    (__attribute__((address_space(3))) unsigned int*)(l), 16, 0, 0)

static __device__ __forceinline__ short f2bf(float f){
  union { float f; unsigned u; } v; v.f = f;
  unsigned r = v.u + 0x7fffu + ((v.u >> 16) & 1u);
  return (short)(r >> 16);
}
static __device__ __forceinline__ float bf2f(short s){
  union { unsigned u; float f; } v; v.u = ((unsigned)(unsigned short)s) << 16;
  return v.f;
}

// ---- X/M fp32 -> fragment-major bf16 hi/lo.  Frag layout: [kt(32)][ntile(256)][64][8]
__global__ __launch_bounds__(256) void kconvA(const float* __restrict__ X,
                                              const float* __restrict__ Mm,
                                              short* __restrict__ XFh, short* __restrict__ XFl,
                                              short* __restrict__ MFh, short* __restrict__ MFl){
  int b = blockIdx.x;                       // 512: src=b>>8, ntile=b&255
  int t = threadIdx.x, w = t >> 6, l = t & 63, quad = l >> 4;
  int srcsel = b >> 8, ntile = b & 255;
  const float* A = srcsel ? Mm : X;
  short* oh = srcsel ? MFh : XFh;
  short* ol = srcsel ? MFl : XFl;
  int row = ntile*16 + (l & 15);
  #pragma unroll
  for (int i = 0; i < 8; i++){
    int kt = w*8 + i;
    const float* p = A + (size_t)row*1024 + kt*32 + quad*8;
    float4 v0 = *(const float4*)p, v1 = *(const float4*)(p + 4);
    float vv[8] = {v0.x,v0.y,v0.z,v0.w,v1.x,v1.y,v1.z,v1.w};
    short8 hh, ll;
    #pragma unroll
    for (int j = 0; j < 8; j++){
      short hb = f2bf(vv[j]); hh[j] = hb; ll[j] = f2bf(vv[j] - bf2f(hb));
    }
    size_t off = ((size_t)kt*256 + ntile)*512 + l*8;
    *(short8*)&oh[off] = hh;
    *(short8*)&ol[off] = ll;
  }
}

// ---- Wq/Wk/Wv fp32 [h][1024][64] -> fragment-major bf16 hi/lo, LDS-staged coalesced
__global__ __launch_bounds__(256) void kconvW2(const float* __restrict__ Wq,
                                               const float* __restrict__ Wk,
                                               const float* __restrict__ Wv,
                                               short* __restrict__ WFh, short* __restrict__ WFl){
  __shared__ float T[128][68];
  int bidx = blockIdx.x, g = blockIdx.y;    // bidx 0..47, g 0..7 (4 kt each)
  int mat = bidx >> 4, h = bidx & 15;
  const float* W = (mat == 0 ? Wq : (mat == 1 ? Wk : Wv)) + (size_t)h*65536;
  int t = threadIdx.x, w = t >> 6, l = t & 63, quad = (l >> 4) & 3, fl = l & 15;
  #pragma unroll
  for (int p = 0; p < 32; p++){
    int idx = p*256 + t, row = idx >> 6, col = idx & 63;
    T[row][col] = W[(size_t)(g*128 + row)*64 + col];
  }
  __syncthreads();
  for (int ktl = 0; ktl < 4; ktl++){
    short8 hh, ll;
    #pragma unroll
    for (int j = 0; j < 8; j++){
      float v = T[ktl*32 + quad*8 + j][w*16 + fl];
      short hb = f2bf(v); hh[j] = hb; ll[j] = f2bf(v - bf2f(hb));
    }
    size_t frag = ((size_t)bidx*32 + g*4 + ktl)*4 + w;
    *(short8*)&WFh[frag*512 + l*8] = hh;
    *(short8*)&WFl[frag*512 + l*8] = ll;
  }
}

// ---- mask -> bitmask (row orientation), int4-vectorized 64MB stream
__global__ __launch_bounds__(256) void kmaskpack(const int* __restrict__ mask,
                                                 unsigned* __restrict__ bits){
  int w = blockIdx.x * 256 + threadIdx.x;          // 4096*128 words
  const int4* p = (const int4*)(mask + (size_t)w * 32);
  unsigned b = 0;
  #pragma unroll
  for (int i = 0; i < 8; i++){
    int4 v = p[i];
    b |= (v.x ? 1u : 0u) << (i*4);
    b |= (v.y ? 1u : 0u) << (i*4 + 1);
    b |= (v.z ? 1u : 0u) << (i*4 + 2);
    b |= (v.w ? 1u : 0u) << (i*4 + 3);
  }
  bits[w] = b;
}

// ---- fp32 [R][C] (z-batch) -> transposed bf16 hi/lo [C][R]  (for Wo)
__global__ __launch_bounds__(256) void ktransw(const float* __restrict__ src,
                                               short* __restrict__ dsth,
                                               short* __restrict__ dstl,
                                               int R, int C){
  __shared__ float tile[32][33];
  size_t boff = (size_t)blockIdx.z * R * C;
  src += boff; dsth += boff; dstl += boff;
  int r0 = blockIdx.y*32, c0 = blockIdx.x*32;
  int t = threadIdx.x, tr = t >> 3, tc = (t & 7)*4;
  const float* s = src + (size_t)(r0 + tr)*C + c0 + tc;
  #pragma unroll
  for (int i = 0; i < 4; i++) tile[tr][tc + i] = s[i];
  __syncthreads();
  short* dh = dsth + (size_t)(c0 + tr)*R + r0 + tc;
  short* dl = dstl + (size_t)(c0 + tr)*R + r0 + tc;
  #pragma unroll
  for (int i = 0; i < 4; i++){
    float v = tile[tc + i][tr];
    short hb = f2bf(v);
    dh[i] = hb; dl[i] = f2bf(v - bf2f(hb));
  }
}

// ---- QKV projection v3 + XCD-locality swap: rb = blockIdx.x (fast dim), so all
//      32 blocks sharing an A-slab (same rb) land on the SAME XCD (lin%8 = rb%8)
//      -> A-panel fetched once per XCD L2, reused by every cb.
__global__ __launch_bounds__(256,3) void kproj3(
    const short* __restrict__ XFh, const short* __restrict__ XFl,
    const short* __restrict__ MFh, const short* __restrict__ MFl,
    const short* __restrict__ WFh, const short* __restrict__ WFl,
    _Float16* __restrict__ QFh, _Float16* __restrict__ QFl,
    _Float16* __restrict__ KFh, _Float16* __restrict__ KFl,
    _Float16* __restrict__ VF)
{
  __shared__ short AhL[4096], AlL[4096], BhL[4096], BlL[4096];   // 32 KB
  int cb = blockIdx.y, rb = blockIdx.x;     // SWAPPED: rb fast -> same-rb same-XCD
  const bool fused = (cb >= 16);            // cb<16: Q head cb; else K+V head cb-16
  int h = fused ? (cb - 16) : cb;
  const short* Ah = fused ? MFh : XFh;
  const short* Al = fused ? MFl : XFl;
  int t = threadIdx.x, w = t >> 6, l = t & 63, quad = l >> 4, ln = l & 15;
  floatx4 acc[2][8] = {};
  for (int kt = 0; kt < 32; kt++){
    __syncthreads();
    size_t abase = ((size_t)kt*256 + rb*8)*512;
    #pragma unroll
    for (int i = 0; i < 2; i++){
      int cidx = i*256 + t;
      GLDS16(Ah + abase + cidx*8, &AhL[(i*256 + w*64)*8]);
      GLDS16(Al + abase + cidx*8, &AlL[(i*256 + w*64)*8]);
    }
    // B frags: Q -> cbW = cb; K -> cbW = 16+h = cb; V -> cbW = 32+h = cb+16
    size_t bb0 = (((size_t)cb*32 + kt)*4)*512;
    GLDS16(WFh + bb0 + t*8, &BhL[(w*64)*8]);
    GLDS16(WFl + bb0 + t*8, &BlL[(w*64)*8]);
    if (fused){
      size_t bb1 = (((size_t)(cb + 16)*32 + kt)*4)*512;
      GLDS16(WFh + bb1 + t*8, &BhL[(256 + w*64)*8]);
      GLDS16(WFl + bb1 + t*8, &BlL[(256 + w*64)*8]);
    }
    __syncthreads();
    short8 ah[2], al[2];
    #pragma unroll
    for (int mt = 0; mt < 2; mt++){
      ah[mt] = *(short8*)&AhL[(w*2 + mt)*512 + l*8];
      al[mt] = *(short8*)&AlL[(w*2 + mt)*512 + l*8];
    }
    {
      short8 bh[4], bl[4];
      #pragma unroll
      for (int nt = 0; nt < 4; nt++){
        bh[nt] = *(short8*)&BhL[nt*512 + l*8];
        bl[nt] = *(short8*)&BlL[nt*512 + l*8];
      }
      #pragma unroll
      for (int mt = 0; mt < 2; mt++)
        #pragma unroll
        for (int nt = 0; nt < 4; nt++){
          acc[mt][nt] = __builtin_amdgcn_mfma_f32_16x16x32_bf16(ah[mt], bh[nt], acc[mt][nt], 0, 0, 0);
          acc[mt][nt] = __builtin_amdgcn_mfma_f32_16x16x32_bf16(ah[mt], bl[nt], acc[mt][nt], 0, 0, 0);
          acc[mt][nt] = __builtin_amdgcn_mfma_f32_16x16x32_bf16(al[mt], bh[nt], acc[mt][nt], 0, 0, 0);
        }
    }
    if (fused){
      short8 bh[4], bl[4];
      #pragma unroll
      for (int nt = 0; nt < 4; nt++){
        bh[nt] = *(short8*)&BhL[(4 + nt)*512 + l*8];
        bl[nt] = *(short8*)&BlL[(4 + nt)*512 + l*8];
      }
      #pragma unroll
      for (int mt = 0; mt < 2; mt++)
        #pragma unroll
        for (int nt = 0; nt < 4; nt++){
          acc[mt][4+nt] = __builtin_amdgcn_mfma_f32_16x16x32_bf16(ah[mt], bh[nt], acc[mt][4+nt], 0, 0, 0);
          acc[mt][4+nt] = __builtin_amdgcn_mfma_f32_16x16x32_bf16(ah[mt], bl[nt], acc[mt][4+nt], 0, 0, 0);
          acc[mt][4+nt] = __builtin_amdgcn_mfma_f32_16x16x32_bf16(al[mt], bh[nt], acc[mt][4+nt], 0, 0, 0);
        }
    }
  }
  int row0 = rb*128;
  if (!fused){
    // Q write: f16 hi/lo frag layout, pre-scaled by log2 e
    #pragma unroll
    for (int mt = 0; mt < 2; mt++)
      #pragma unroll
      for (int nt = 0; nt < 4; nt++)
        #pragma unroll
        for (int rg = 0; rg < 4; rg++){
          int n = row0 + w*32 + mt*16 + quad*4 + rg;
          int c = nt*16 + ln;
          float v = acc[mt][nt][rg] * LOG2E;
          _Float16 hi = (_Float16)v;
          _Float16 lo = (_Float16)(v - (float)hi);
          int lane2 = (n & 15) + (((c >> 3) & 3) << 4);
          size_t off = (((size_t)h*256 + (n >> 4))*2 + (c >> 5))*512 + lane2*8 + (c & 7);
          QFh[off] = hi; QFl[off] = lo;
        }
  } else {
    // K write from acc[.][0..3]
    #pragma unroll
    for (int mt = 0; mt < 2; mt++)
      #pragma unroll
      for (int nt = 0; nt < 4; nt++)
        #pragma unroll
        for (int rg = 0; rg < 4; rg++){
          int n = row0 + w*32 + mt*16 + quad*4 + rg;
          int c = nt*16 + ln;
          float v = acc[mt][nt][rg];
          _Float16 hi = (_Float16)v;
          _Float16 lo = (_Float16)(v - (float)hi);
          int lane2 = (n & 15) + (((c >> 3) & 3) << 4);
          size_t off = (((size_t)h*256 + (n >> 4))*2 + (c >> 5))*512 + lane2*8 + (c & 7);
          KFh[off] = hi; KFl[off] = lo;
        }
    // V write from acc[.][4..7]: K=16 A-frag layout
    #pragma unroll
    for (int mt = 0; mt < 2; mt++)
      #pragma unroll
      for (int ntv = 0; ntv < 4; ntv++){
        union { fp16x2 h2[2]; unsigned u2[2]; } pu;
        pu.h2[0] = __builtin_amdgcn_cvt_pkrtz(acc[mt][4+ntv][0], acc[mt][4+ntv][1]);
        pu.h2[1] = __builtin_amdgcn_cvt_pkrtz(acc[mt][4+ntv][2], acc[mt][4+ntv][3]);
        size_t base = (((size_t)h*32 + rb)*16 + ntv*4 + w)*512;
        *(uint2*)&VF[base + (quad*16 + ln)*8 + mt*4] = *(uint2*)&pu.u2[0];
      }
  }
}

// ---- flash attention v8 (R3 version, 219us): 64-row q blocks, K dbuf prefetch,
//      V staged post-PV, setprio on MFMA clusters, per-lane lst partials.
__global__ __launch_bounds__(256,4) void kattn8(
    const _Float16* __restrict__ QFh, const _Float16* __restrict__ QFl,
    const _Float16* __restrict__ KFh, const _Float16* __restrict__ KFl,
    const _Float16* __restrict__ VF, const unsigned* __restrict__ bits,
    short* __restrict__ Ows)
{
  __shared__ _Float16 KBh[2][4096], KBl[2][4096], VB[4096];     // 40 KB
  int bx = blockIdx.x, h = bx & 15, qb = bx >> 4, q0 = qb*64;   // qb 0..63
  int t = threadIdx.x, w = t >> 6, l = t & 63, quad = l >> 4, ln = l & 15;

  // Q as B-fragments (col q = ln, k = quad*8+j per 32-d chunk); wave w owns 16 q rows
  half8 qh[2], ql[2];
  #pragma unroll
  for (int kc = 0; kc < 2; kc++){
    size_t off = (((size_t)h*256 + qb*4 + w)*2 + kc)*512 + l*8;
    qh[kc] = *(const half8*)&QFh[off];
    ql[kc] = *(const half8*)&QFl[off];
  }

  floatx4 o[4] = {};                          // O^T: lane q=ln, v = vt*16+quad*4+rg
  float mst = -1e30f, lst = 0.f;              // lst: per-lane partial (reduced at end)

  const size_t hb = (size_t)h*262144;
  const int cidx0 = t, cidx1 = 256 + t;
  const int ld0 = (w*64)*8, ld1 = (256 + w*64)*8;

  // ---- prologue: stage K[0] (hi+lo) + V[0], prefetch mask[0]
  {
    GLDS16(KFh + hb + cidx0*8, &KBh[0][ld0]);
    GLDS16(KFh + hb + cidx1*8, &KBh[0][ld1]);
    GLDS16(KFl + hb + cidx0*8, &KBl[0][ld0]);
    GLDS16(KFl + hb + cidx1*8, &KBl[0][ld1]);
    #pragma unroll
    for (int i = 0; i < 2; i++){
      int cidx = i*256 + t;
      int lu = cidx >> 6, uoff = (cidx & 63)*8;
      int gu = (lu >> 1)*4 + (lu & 1);                  // vhalf = 0
      GLDS16(VF + hb + (size_t)gu*512 + uoff, &VB[(i*256 + w*64)*8]);
    }
  }
  uint2 mwv = *(const uint2*)&bits[(size_t)(q0 + w*16 + ln)*128];
  __syncthreads();                                      // drains K0/V0

  int cur = 0;
  for (int kt = 0; kt < 64; kt++){
    int ktn = (kt + 1) & 63;                            // wraps -> always valid mem
    // ---- prefetch K[ktn] into the other buffer (covered by QK+softmax below)
    size_t kbn = hb + (size_t)ktn*4096;
    GLDS16(KFh + kbn + cidx0*8, &KBh[cur^1][ld0]);
    GLDS16(KFh + kbn + cidx1*8, &KBh[cur^1][ld1]);
    GLDS16(KFl + kbn + cidx0*8, &KBl[cur^1][ld0]);
    GLDS16(KFl + kbn + cidx1*8, &KBl[cur^1][ld1]);
    uint2 mwn = *(const uint2*)&bits[(size_t)(q0 + w*16 + ln)*128 + ktn*2];

    // ---- S^T = Khi*Qhi + Klo*Qhi + Khi*Qlo  (log2-domain; from KB[cur])
    floatx4 st[4] = {};
    __builtin_amdgcn_s_setprio(1);
    #pragma unroll
    for (int kc = 0; kc < 2; kc++)
      #pragma unroll
      for (int m8 = 0; m8 < 4; m8++){
        half8 kh = *(half8*)&KBh[cur][(m8*2 + kc)*512 + l*8];
        half8 kl = *(half8*)&KBl[cur][(m8*2 + kc)*512 + l*8];
        st[m8] = __builtin_amdgcn_mfma_f32_16x16x32_f16(kh, qh[kc], st[m8], 0, 0, 0);
        st[m8] = __builtin_amdgcn_mfma_f32_16x16x32_f16(kl, qh[kc], st[m8], 0, 0, 0);
        st[m8] = __builtin_amdgcn_mfma_f32_16x16x32_f16(kh, ql[kc], st[m8], 0, 0, 0);
      }
    __builtin_amdgcn_s_setprio(0);

    // ---- mask + online softmax (register bit-test), p = 2^(s - m)
    {
      const unsigned mwp[2] = {mwv.x, mwv.y};
      #pragma unroll
      for (int m8 = 0; m8 < 4; m8++){
        unsigned nib = (mwp[m8 >> 1] >> ((m8 & 1)*16 + quad*4)) & 15u;
        #pragma unroll
        for (int rg = 0; rg < 4; rg++)
          if (!((nib >> rg) & 1u)) st[m8][rg] = -1e30f;
      }
      // max tree (max3-fusable)
      float a0 = fmaxf(fmaxf(st[0][0], st[0][1]), fmaxf(st[0][2], st[0][3]));
      float a1 = fmaxf(fmaxf(st[1][0], st[1][1]), fmaxf(st[1][2], st[1][3]));
      float a2 = fmaxf(fmaxf(st[2][0], st[2][1]), fmaxf(st[2][2], st[2][3]));
      float a3 = fmaxf(fmaxf(st[3][0], st[3][1]), fmaxf(st[3][2], st[3][3]));
      float mx = fmaxf(fmaxf(a0, a1), fmaxf(a2, a3));
      mx = fmaxf(mx, __shfl_xor(mx, 16));
      mx = fmaxf(mx, __shfl_xor(mx, 32));
      // defer-max (T13): skip O-rescale while max growth <= 8 (log2 dom, p<=256)
      if (__any(mx > mst + 8.0f)){
        float mnew = fmaxf(mst, mx);
        float alpha = exp2f(mst - mnew);
        mst = mnew;
        lst *= alpha;
        #pragma unroll
        for (int vt = 0; vt < 4; vt++) o[vt] *= alpha;
      }
      float ssum = 0.f;
      #pragma unroll
      for (int m8 = 0; m8 < 4; m8++)
        #pragma unroll
        for (int rg = 0; rg < 4; rg++){
          float p = exp2f(st[m8][rg] - mst);
          st[m8][rg] = p; ssum += p;
        }
      lst += ssum;            // per-lane partial; quad-uniform alpha keeps it exact
    }
    mwv = mwn;

    __syncthreads();    // #1: V[kt] (staged end of prev iter) + K[ktn] drained

    // ---- PV: P C-layout == B-operand of 16x16x16f16 (k = quad*4+rg)
    __builtin_amdgcn_s_setprio(1);
    #pragma unroll
    for (int p = 0; p < 2; p++){
      half8 vfp[4];
      #pragma unroll
      for (int vt = 0; vt < 4; vt++)
        vfp[vt] = *(half8*)&VB[((vt*2 + p)*512) + l*8];
      #pragma unroll
      for (int sub = 0; sub < 2; sub++){
        int m8 = p*2 + sub;
        union { fp16x2 h2[2]; half4 h4; } pu;
        pu.h2[0] = __builtin_amdgcn_cvt_pkrtz(st[m8][0], st[m8][1]);
        pu.h2[1] = __builtin_amdgcn_cvt_pkrtz(st[m8][2], st[m8][3]);
        #pragma unroll
        for (int vt = 0; vt < 4; vt++){
          half4 va = sub ? __builtin_shufflevector(vfp[vt], vfp[vt], 4,5,6,7)
                         : __builtin_shufflevector(vfp[vt], vfp[vt], 0,1,2,3);
          o[vt] = __builtin_amdgcn_mfma_f32_16x16x16f16(va, pu.h4, o[vt], 0, 0, 0);
        }
      }
    }
    __builtin_amdgcn_s_setprio(0);

    __syncthreads();    // #2: all waves done reading VB

    // ---- stage V[ktn] (covered by next iter's QK+softmax)
    {
      size_t vbn = hb + (size_t)(ktn >> 1)*8192;
      int vhalf = (ktn & 1)*2;
      #pragma unroll
      for (int i = 0; i < 2; i++){
        int cidx = i*256 + t;
        int lu = cidx >> 6, uoff = (cidx & 63)*8;
        int gu = (lu >> 1)*4 + vhalf + (lu & 1);
        GLDS16(VF + vbn + (size_t)gu*512 + uoff, &VB[(i*256 + w*64)*8]);
      }
    }
    cur ^= 1;
  }

  // epilogue: reduce lst across the quad-group, normalize, O^T -> Ows
  {
    lst += __shfl_xor(lst, 16);
    lst += __shfl_xor(lst, 32);
    float inv = (lst > 0.f) ? (1.f / lst) : 0.f;
    int n = q0 + w*16 + ln;
    #pragma unroll
    for (int vt = 0; vt < 4; vt++){
      short4v pk;
      #pragma unroll
      for (int rg = 0; rg < 4; rg++) pk[rg] = f2bf(o[vt][rg]*inv);
      *(short4v*)&Ows[(size_t)n*1024 + h*64 + vt*16 + quad*4] = pk;
    }
  }
}

// ---- Y[f32] = O[4096x1024 bf16] @ Wot[1024x1024 bf16 B^T rows]
//      XCD-locality swap: rb = blockIdx.x (fast) -> same-rb blocks same XCD.
__global__ __launch_bounds__(256,2) void kfinal(const short* __restrict__ Ain,
                                                const short* __restrict__ Bt,
                                                float* __restrict__ Y)
{
  __shared__ short Al[128*48];
  __shared__ short Bl[64*48];
  int cb = blockIdx.y, rb = blockIdx.x;     // SWAPPED
  int row0 = rb*128, col0 = cb*64;
  int t = threadIdx.x, w = t >> 6, l = t & 63, quad = l >> 4, ln = l & 15;
  floatx4 acc[2][4] = {};
  for (int d0 = 0; d0 < 1024; d0 += 32){
    #pragma unroll
    for (int i = 0; i < 2; i++){
      int u = t + i*256, r = u >> 2, s = u & 3;
      *(int4*)&Al[r*48 + s*8] = *(const int4*)&Ain[(size_t)(row0 + r)*1024 + d0 + s*8];
    }
    { int r = t >> 2, s = t & 3;
      *(int4*)&Bl[r*48 + s*8] = *(const int4*)&Bt[(size_t)(col0 + r)*1024 + d0 + s*8]; }
    __syncthreads();
    short8 bf[4];
    #pragma unroll
    for (int nt = 0; nt < 4; nt++) bf[nt] = *(short8*)&Bl[(nt*16 + ln)*48 + quad*8];
    #pragma unroll
    for (int mt = 0; mt < 2; mt++){
      short8 af = *(short8*)&Al[(w*32 + mt*16 + ln)*48 + quad*8];
      #pragma unroll
      for (int nt = 0; nt < 4; nt++)
        acc[mt][nt] = __builtin_amdgcn_mfma_f32_16x16x32_bf16(af, bf[nt], acc[mt][nt], 0, 0, 0);
    }
    __syncthreads();
  }
  #pragma unroll
  for (int mt = 0; mt < 2; mt++)
    #pragma unroll
    for (int nt = 0; nt < 4; nt++)
      #pragma unroll
      for (int rg = 0; rg < 4; rg++){
        int n = row0 + w*32 + mt*16 + quad*4 + rg;
        int c = col0 + nt*16 + ln;
        Y[(size_t)n*1024 + c] = acc[mt][nt][rg];
      }
}

extern "C" void kernel_launch(void* const* d_in, const int* in_sizes, int n_in,
                              void* d_out, int out_size, void* d_ws, size_t ws_size,
                              hipStream_t stream){
  (void)in_sizes; (void)n_in; (void)out_size; (void)ws_size;
  const float* X    = (const float*)d_in[0];
  const float* Mm   = (const float*)d_in[1];
  const int*   mask = (const int*)d_in[2];
  const float* Wq   = (const float*)d_in[3];
  const float* Wk   = (const float*)d_in[4];
  const float* Wv   = (const float*)d_in[5];
  const float* Wo   = (const float*)d_in[6];
  float* Y = (float*)d_out;
  char* ws = (char*)d_ws;
  const size_t MB = 1024*1024;
  short*    XFh   = (short*)   (ws +  0*MB);   // dead after kproj3
  short*    XFl   = (short*)   (ws +  8*MB);   // dead after kproj3
  short*    MFh   = (short*)   (ws + 16*MB);
  short*    MFl   = (short*)   (ws + 24*MB);
  short*    WFh   = (short*)   (ws + 32*MB);   // 6MB
  short*    WFl   = (short*)   (ws + 38*MB);   // 6MB
  unsigned* bits  = (unsigned*)(ws + 44*MB);   // 2MB  [4096 n][128 kw]
  _Float16* QFh   = (_Float16*)(ws + 46*MB);
  _Float16* QFl   = (_Float16*)(ws + 54*MB);
  _Float16* KFh   = (_Float16*)(ws + 62*MB);
  _Float16* KFl   = (_Float16*)(ws + 70*MB);
  _Float16* VF    = (_Float16*)(ws + 78*MB);   // 8MB, K=16 A-frag layout
  short*    Ows   = (short*)   (ws +  0*MB);   // alias XFh (post-kproj3)
  short*    Wot   = (short*)   (ws +  8*MB);   // alias XFl
  short*    Wotl  = (short*)   (ws + 10*MB);

  kconvA<<<512, 256, 0, stream>>>(X, Mm, XFh, XFl, MFh, MFl);
  kconvW2<<<dim3(48,8), 256, 0, stream>>>(Wq, Wk, Wv, WFh, WFl);
  kmaskpack<<<2048, 256, 0, stream>>>(mask, bits);
  kproj3<<<dim3(32,32), 256, 0, stream>>>(XFh, XFl, MFh, MFl, WFh, WFl,
                                          QFh, QFl, KFh, KFl, VF);
  ktransw<<<dim3(32,32,1), 256, 0, stream>>>(Wo, Wot, Wotl, 1024, 1024);
  kattn8<<<1024, 256, 0, stream>>>(QFh, QFl, KFh, KFl, VF, bits, Ows);
  kfinal<<<dim3(32,16), 256, 0, stream>>>(Ows, Wot, Y);
}